// Round 8
// baseline (198.890 us; speedup 1.0000x reference)
//
#include <hip/hip_runtime.h>
#include <hip/hip_bf16.h>

// GRNNTransformGated, round 28: R27 split-t body + launch bounds back to
// (256,2). R27 proved the 36KB/4-block structure (occ 33%, level11 -5us)
// but (256,4) made the allocator target 64 VGPR -> az[4][4] spilled
// (WRITE 16.4->27.4MB). Occupancy=min(LDS,VGPR) and LDS already caps at 4;
// (256,2) lets the allocator keep az resident (~104 VGPR -> 4 waves/SIMD).
// Post-mortem ledger:
//  R4: agent-scope spin grid barriers ~137us each -> never.
//  R12+R27: VGPR budget below live-acc arithmetic == spill. Spill tell =
//      WRITE_SIZE >> data written. (256,4) made allocator target 64 VGPR.
//      RULE: never use launch_bounds to chase occupancy the LDS limit
//      already provides; only ensure the cap doesn't block it.
//  R13/R14: fusing big levels at 1-block/CU occupancy loses.
//  R15: +8KB LDS cost a block/CU on big levels. s_hH aliases s_t in glob.
//  R16+R25: per-lane loads feeding MFMA put global latency on the MFMA dep
//      chain -> regression. Cooperative staging + barrier wins. Direct 8B
//      stores at 128B stride lose to LDS-round-trip coalesced 16B stores.
//  R17/R18: 198us plateau. R19: B=512 fused chain regressed.
//  R21 FAILED: weight prefetch under (256,2) -> compiler sank loads.
//  R22 FAILED: resident weights under (256,2): VGPR pinned, 700MB scratch.
//  R23 FAILED: merged-level kernel spilled (cross-tile scheduling).
//  R26 WIN (194.9): R24 bodies + one convert kernel + CH_LDS fused chain.
//  R27 MIXED (197.1): 36KB split-t worked (occ 17.7->33, level11 54.7->
//      49.5) but (256,4) spilled az (+11MB scratch) + 131us scratch-setup
//      outlier on level_kernel. This round removes only the spill.
// Carried: in-place up regions in u_all; exp2-folded W_r/b_r/W_z/b_z;
// operand-swapped MFMA (D = W @ act^T); coalesced up-store via LDS
// round-trip; MFMA-u; j=11 computes level-12 children u from c16; c16 in
// u12's never-used region; fused (256,1) chain j=8..0 with resident
// weights + CH_LDS/STORE_U.

#define LOG2E 1.4426950408889634f
#define OSTR 76   // out-staging row stride (elements)

typedef __bf16 bf16x8 __attribute__((ext_vector_type(8)));
typedef unsigned short u16x8 __attribute__((ext_vector_type(8)));
typedef float f32x4 __attribute__((ext_vector_type(4)));
typedef unsigned short bfr;   // raw bf16 bits

__device__ __forceinline__ float bfr2f(bfr v) { return __uint_as_float(((unsigned)v) << 16); }
__device__ __forceinline__ bfr f2bfr(float f) {
    __hip_bfloat16 h = __float2bfloat16(f);
    return __builtin_bit_cast(bfr, h);
}
__device__ __forceinline__ float fexp2(float x) {
#if __has_builtin(__builtin_amdgcn_exp2f)
    return __builtin_amdgcn_exp2f(x);
#else
    return exp2f(x);
#endif
}
__device__ __forceinline__ float frcp(float x) {
#if __has_builtin(__builtin_amdgcn_rcpf)
    return __builtin_amdgcn_rcpf(x);
#else
    return 1.f / x;
#endif
}

// fragment-order address (elements): frag (Mt,kt), lane (ln,q), 8 elems
__device__ __forceinline__ int fidx(int Mt, int kt, int q, int ln, int KT) {
    return ((((Mt * KT + kt) * 4 + q) * 16 + ln) * 8);
}

// level-j up region start (elements) within u_all
__device__ __host__ __forceinline__ size_t lvloff(int j) {
    return (size_t)((64 << j) - 64) * 64;
}

__device__ __forceinline__ void pack_one(const float* __restrict__ W, bfr* __restrict__ dst,
                                         int d, int K, float scale) {
    int KT = K >> 5;
    int j = d & 7, lnc = (d >> 3) & 15, q = (d >> 7) & 3;
    int t1 = d >> 9;
    int kt = t1 % KT, ntile = t1 / KT;
    int ncol = ntile * 16 + lnc;
    int k = kt * 32 + q * 8 + j;
    dst[d] = f2bfr(W[(size_t)ncol * K + k] * scale);
}

// One prologue kernel: weights pack + contents->c16. Grid 2048x256.
__global__ void convert_inputs(
    const float* __restrict__ c, bfr* __restrict__ c16,
    const float* __restrict__ Wr, const float* __restrict__ Wh,
    const float* __restrict__ Wz, const float* __restrict__ Wu,
    const float* __restrict__ br, const float* __restrict__ bz,
    bfr* __restrict__ wr, bfr* __restrict__ wh, bfr* __restrict__ wz,
    bfr* __restrict__ wu, float* __restrict__ brs, float* __restrict__ bzs)
{
    int i = blockIdx.x * 256 + threadIdx.x;   // 524288 threads
    if (i < 524224) {   // contents row -> padded bf16 row (16B)
        const float* cp = c + (size_t)i * 7;
        ushort v[8];
#pragma unroll
        for (int k = 0; k < 7; ++k) v[k] = f2bfr(cp[k]);
        v[7] = 0;
        *(uint4*)&c16[(size_t)i * 8] = *(const uint4*)v;
    }
    if (i < 36864) pack_one(Wr, wr, i, 192, LOG2E);
    if (i < 12288) pack_one(Wh, wh, i, 192, 1.f);
    if (i < 65536) pack_one(Wz, wz, i, 256, LOG2E);
    if (i < 2048) {   // W_u (64x7) -> frag order K=32, zero-padded
        int j = i & 7, lnc = (i >> 3) & 15, q = (i >> 7) & 3, ntile = i >> 9;
        int k = q * 8 + j, ncol = ntile * 16 + lnc;
        wu[i] = (k < 7) ? f2bfr(Wu[ncol * 7 + k]) : (bfr)0;
    }
    if (i < 192) brs[i] = br[i] * LOG2E;
    if (i < 256) bzs[i] = bz[i] * LOG2E;
}

// Stage `rows` pre-converted contents rows as bf16 B-frags (K=32 padded).
__device__ __forceinline__ void stage_c16(const bfr* __restrict__ c16src, int rows,
                                          bfr* s_c) {
    const int tid = threadIdx.x;
    for (int t = tid; t < rows * 4; t += 256) {
        int row = t >> 2, qg = t & 3;
        uint4 v = {0u, 0u, 0u, 0u};
        if (qg == 0) v = *(const uint4*)&c16src[(size_t)row * 8];
        *(uint4*)&s_c[(((row >> 4) * 4 + qg) * 16 + (row & 15)) * 8] = v;
    }
}

// Build a contents B-fragment directly from c16 (single 16B load).
// Used ONLY in the (256,1) fused tiles (R16/R25: staged wins in glob).
__device__ __forceinline__ bf16x8 load_c_frag16(const bfr* __restrict__ c16,
                                                size_t grow, bool active) {
    uint4 v = {0u, 0u, 0u, 0u};
    if (active) v = *(const uint4*)&c16[grow * 8];
    return __builtin_bit_cast(bf16x8, v);
}

// Coalesced up-store epilogue via LDS round-trip (internal syncs).
__device__ __forceinline__ void store_up_coalesced(
    int row0, int rows, bfr* __restrict__ u_io,
    const ushort (&ovv)[4][4], int Mtn, bfr* s_t)
{
    const int tid = threadIdx.x;
    const int lane = tid & 63, w = tid >> 6;
    const int ln = lane & 15, q = lane >> 4;
    const int colbase = w * 16 + q * 4;
    __syncthreads();
#pragma unroll
    for (int Mt = 0; Mt < 4; ++Mt) {
        if (Mt < Mtn) {
            int row = Mt * 16 + ln;
            if (row < rows)
                *(uint2*)&s_t[row * OSTR + colbase] = *(const uint2*)ovv[Mt];
        }
    }
    __syncthreads();
#pragma unroll
    for (int it = 0; it < 2; ++it) {
        int idx = it * 256 + tid;
        int row = idx >> 3, ck = idx & 7;
        if (row < rows)
            *(uint4*)&u_io[(size_t)(row0 + row) * 64 + ck * 8] =
                *(const uint4*)&s_t[row * OSTR + ck * 8];
    }
}

// mm_u: u = relu(c @ W_u^T) via MFMA from staged c frags into s_hhu (kt4..5).
__device__ __forceinline__ void mmu_own(const bfr* s_c, bfr* s_hhu, bf16x8 awu,
                                        f32x4 bu4, int Mtn, int ln, int q,
                                        int colbase) {
#pragma unroll
    for (int Mt = 0; Mt < 4; ++Mt) {
        if (Mt < Mtn) {
            bf16x8 Bc = *(const bf16x8*)&s_c[((Mt * 4 + q) * 16 + ln) * 8];
            f32x4 acc = {0.f, 0.f, 0.f, 0.f};
            acc = __builtin_amdgcn_mfma_f32_16x16x32_bf16(awu, Bc, acc, 0, 0, 0);
            int kk = 128 + colbase;
            int addr = fidx(Mt, kk >> 5, (kk >> 3) & 3, ln, 6) + (kk & 7);
            ushort uv[4];
#pragma unroll
            for (int r = 0; r < 4; ++r) uv[r] = f2bfr(fmaxf(acc[r] + bu4[r], 0.f));
            *(uint2*)&s_hhu[addr] = *(const uint2*)uv;
        }
    }
}

// ===== glob tile (R27 body): split-t mm1/mm2 K-halves, 36KB LDS =====
// s_hhu 24KB (full), s_t 12KB (t half-buffer / stages / hH alias / out rows).
// mm1 col-tiles resliced T = i*4 + w (wave-uniform branch); t stored by
// kt-tile within the half (KT=3). mm2 accumulates kt 0..2 then 3..5 into
// hacc (f32 order preserved -> bit-identical).
template <bool CHILD_U>
__device__ __forceinline__ void tile_glob(
    int row0,
    const bfr* __restrict__ ch, const bfr* __restrict__ c16_child,
    const bfr* __restrict__ c16_own, bfr* __restrict__ u_io,
    const bfr* __restrict__ wu, const float* __restrict__ b_u,
    const bfr* __restrict__ wr, const float* __restrict__ brs,
    const bfr* __restrict__ wh, const float* __restrict__ b_h,
    const bfr* __restrict__ wz, const float* __restrict__ bzs,
    bfr* s_hhu, bfr* s_t)
{
    bfr* s_hH = s_t;   // alias: h_H (4KB) written only after t halves dead
    const int tid = threadIdx.x;
    const int lane = tid & 63, w = tid >> 6;
    const int ln = lane & 15, q = lane >> 4;
    const int colbase = w * 16 + q * 4;

    // ---- stage children + own contents (cooperative) ----
    if (!CHILD_U) {
#pragma unroll
        for (int it = 0; it < 4; ++it) {
            int idx = it * 256 + tid;
            int lns = idx & 15, qs = (idx >> 4) & 3, kts = (idx >> 6) & 3, Mts = idx >> 8;
            int row = Mts * 16 + lns;
            int k = kts * 32 + qs * 8;
            const bfr* src = (k < 64)
                ? ch + (size_t)(2 * (row0 + row)) * 64 + k
                : ch + (size_t)(2 * (row0 + row) + 1) * 64 + (k - 64);
            *(uint4*)&s_hhu[fidx(Mts, kts, qs, lns, 6)] = *(const uint4*)src;
        }
    } else {
        stage_c16(c16_child + (size_t)(2 * row0) * 8, 128, s_t + 2048);
    }
    stage_c16(c16_own + (size_t)row0 * 8, 64, s_t);
    __syncthreads();   // B1

    // ---- mm_u ----
    {
        bf16x8 awu = *(const bf16x8*)&wu[fidx(w, 0, q, ln, 1)];
        f32x4 bu4 = *(const f32x4*)&b_u[colbase];
        if (CHILD_U) {
#pragma unroll
            for (int Mt = 0; Mt < 8; ++Mt) {
                bf16x8 Bc = *(const bf16x8*)&s_t[2048 + (((Mt * 4 + q) * 16 + ln) * 8)];
                f32x4 acc = {0.f, 0.f, 0.f, 0.f};
                acc = __builtin_amdgcn_mfma_f32_16x16x32_bf16(awu, Bc, acc, 0, 0, 0);
                int crow = Mt * 16 + ln;
                int row = crow >> 1;
                int kk = (crow & 1) * 64 + colbase;
                int addr = fidx(row >> 4, kk >> 5, (kk >> 3) & 3, row & 15, 6) + (kk & 7);
                ushort uv[4];
#pragma unroll
                for (int r = 0; r < 4; ++r) uv[r] = f2bfr(fmaxf(acc[r] + bu4[r], 0.f));
                *(uint2*)&s_hhu[addr] = *(const uint2*)uv;
            }
        }
        mmu_own(s_t, s_hhu, awu, bu4, 4, ln, q, colbase);
    }
    __syncthreads();   // B2 (stage reads done; t halves may overwrite s_t)

    // ---- mm1/mm2 in two kt-halves through the 12KB t buffer ----
    f32x4 hacc[4];
#pragma unroll
    for (int Mt = 0; Mt < 4; ++Mt) hacc[Mt] = (f32x4){0.f, 0.f, 0.f, 0.f};
#pragma unroll
    for (int h = 0; h < 2; ++h) {
        // mm1 half h: col-tiles T = i*4+w with T in [6h, 6h+6)
#pragma unroll
        for (int i = 0; i < 3; ++i) {
            int T = i * 4 + w;
            if (T >= 6 * h && T < 6 * (h + 1)) {   // wave-uniform branch
                bf16x8 Af[6];
#pragma unroll
                for (int kt = 0; kt < 6; ++kt)
                    Af[kt] = *(const bf16x8*)&wr[fidx(T, kt, q, ln, 6)];
                int cb1 = T * 16 + q * 4;
                f32x4 br4 = *(const f32x4*)&brs[cb1];
#pragma unroll
                for (int Mt = 0; Mt < 4; ++Mt) {
                    f32x4 acc = {0.f, 0.f, 0.f, 0.f};
#pragma unroll
                    for (int kt = 0; kt < 6; ++kt)
                        acc = __builtin_amdgcn_mfma_f32_16x16x32_bf16(
                            Af[kt], *(const bf16x8*)&s_hhu[fidx(Mt, kt, q, ln, 6)], acc, 0, 0, 0);
                    int addrh = fidx(Mt, cb1 >> 5, (cb1 >> 3) & 3, ln, 6) + (cb1 & 7);
                    int addrt = fidx(Mt, (T >> 1) - 3 * h, (cb1 >> 3) & 3, ln, 3) + (cb1 & 7);
                    ushort hh[4], tt[4];
                    *(uint2*)hh = *(const uint2*)&s_hhu[addrh];
#pragma unroll
                    for (int r = 0; r < 4; ++r) {
                        float e = fexp2(-(acc[r] + br4[r]));
                        tt[r] = f2bfr(frcp(1.f + e) * bfr2f(hh[r]));
                    }
                    *(uint2*)&s_t[addrt] = *(const uint2*)tt;
                }
            }
        }
        __syncthreads();   // t half ready
        // mm2 half h: accumulate kt = 3h..3h+2
        {
            bf16x8 Ah[3];
#pragma unroll
            for (int k3 = 0; k3 < 3; ++k3)
                Ah[k3] = *(const bf16x8*)&wh[fidx(w, 3 * h + k3, q, ln, 6)];
#pragma unroll
            for (int Mt = 0; Mt < 4; ++Mt) {
#pragma unroll
                for (int k3 = 0; k3 < 3; ++k3)
                    hacc[Mt] = __builtin_amdgcn_mfma_f32_16x16x32_bf16(
                        Ah[k3], *(const bf16x8*)&s_t[fidx(Mt, k3, q, ln, 3)], hacc[Mt], 0, 0, 0);
            }
        }
        __syncthreads();   // half reads done (next half / hH may overwrite)
    }

    // ---- hH write (aliased s_t; t dead) ----
    {
        f32x4 bh4 = *(const f32x4*)&b_h[colbase];
#pragma unroll
        for (int Mt = 0; Mt < 4; ++Mt) {
            int addr = fidx(Mt, colbase >> 5, (colbase >> 3) & 3, ln, 2) + (colbase & 7);
            ushort hv[4];
#pragma unroll
            for (int r = 0; r < 4; ++r) hv[r] = f2bfr(fmaxf(hacc[Mt][r] + bh4[r], 0.f));
            *(uint2*)&s_hH[addr] = *(const uint2*)hv;
        }
    }
    __syncthreads();

    // ---- mm3 (g-outer, az[4][4] resident) + gate ----
    {
        f32x4 az[4][4];
#pragma unroll
        for (int Mt = 0; Mt < 4; ++Mt)
#pragma unroll
            for (int g = 0; g < 4; ++g) az[Mt][g] = (f32x4){0.f, 0.f, 0.f, 0.f};
#pragma unroll
        for (int g = 0; g < 4; ++g) {
            bf16x8 Aw[8];
#pragma unroll
            for (int kt = 0; kt < 8; ++kt)
                Aw[kt] = *(const bf16x8*)&wz[fidx(g * 4 + w, kt, q, ln, 8)];
#pragma unroll
            for (int Mt = 0; Mt < 4; ++Mt) {
                f32x4 acc = az[Mt][g];
                acc = __builtin_amdgcn_mfma_f32_16x16x32_bf16(
                    Aw[0], *(const bf16x8*)&s_hH[fidx(Mt, 0, q, ln, 2)], acc, 0, 0, 0);
                acc = __builtin_amdgcn_mfma_f32_16x16x32_bf16(
                    Aw[1], *(const bf16x8*)&s_hH[fidx(Mt, 1, q, ln, 2)], acc, 0, 0, 0);
#pragma unroll
                for (int kt = 0; kt < 6; ++kt)
                    acc = __builtin_amdgcn_mfma_f32_16x16x32_bf16(
                        Aw[2 + kt], *(const bf16x8*)&s_hhu[fidx(Mt, kt, q, ln, 6)], acc, 0, 0, 0);
                az[Mt][g] = acc;
            }
        }
        f32x4 bz0 = *(const f32x4*)&bzs[colbase];
        f32x4 bz1 = *(const f32x4*)&bzs[64 + colbase];
        f32x4 bz2 = *(const f32x4*)&bzs[128 + colbase];
        f32x4 bz3 = *(const f32x4*)&bzs[192 + colbase];
        ushort ovv[4][4];
#pragma unroll
        for (int Mt = 0; Mt < 4; ++Mt) {
            int aH = fidx(Mt, colbase >> 5, (colbase >> 3) & 3, ln, 2) + (colbase & 7);
            int a0 = fidx(Mt, colbase >> 5, (colbase >> 3) & 3, ln, 6) + (colbase & 7);
            int c1 = 64 + colbase, c2 = 128 + colbase;
            int a1 = fidx(Mt, c1 >> 5, (c1 >> 3) & 3, ln, 6) + (c1 & 7);
            int a2 = fidx(Mt, c2 >> 5, (c2 >> 3) & 3, ln, 6) + (c2 & 7);
            ushort hHv[4], u0[4], u1[4], u2[4];
            *(uint2*)hHv = *(const uint2*)&s_hH[aH];
            *(uint2*)u0 = *(const uint2*)&s_hhu[a0];
            *(uint2*)u1 = *(const uint2*)&s_hhu[a1];
            *(uint2*)u2 = *(const uint2*)&s_hhu[a2];
#pragma unroll
            for (int r = 0; r < 4; ++r) {
                float e0 = fexp2(az[Mt][0][r] + bz0[r]);
                float e1 = fexp2(az[Mt][1][r] + bz1[r]);
                float e2 = fexp2(az[Mt][2][r] + bz2[r]);
                float e3 = fexp2(az[Mt][3][r] + bz3[r]);
                float inv = frcp(e0 + e1 + e2 + e3);
                float v = (e0 * bfr2f(hHv[r]) + e1 * bfr2f(u0[r]) +
                           e2 * bfr2f(u1[r]) + e3 * bfr2f(u2[r])) * inv;
                ovv[Mt][r] = f2bfr(v);
            }
        }
        store_up_coalesced(row0, 64, u_io, ovv, 4, s_t);
    }
}

__global__ __launch_bounds__(256, 2) void level11_kernel(
    const bfr* __restrict__ c16_12, const bfr* __restrict__ c16_11,
    bfr* __restrict__ u_io,
    const bfr* __restrict__ wr, const float* __restrict__ brs,
    const bfr* __restrict__ wh, const float* __restrict__ b_h,
    const bfr* __restrict__ wz, const float* __restrict__ bzs,
    const bfr* __restrict__ wu, const float* __restrict__ b_u)
{
    __shared__ bfr s_hhu[12288];
    __shared__ bfr s_t[6144];
    tile_glob<true>(blockIdx.x * 64, nullptr, c16_12, c16_11, u_io,
                    wu, b_u, wr, brs, wh, b_h, wz, bzs, s_hhu, s_t);
}

__global__ __launch_bounds__(256, 2) void level_kernel(
    const bfr* __restrict__ ch, const bfr* __restrict__ c16_own,
    bfr* __restrict__ u_io,
    const bfr* __restrict__ wr, const float* __restrict__ brs,
    const bfr* __restrict__ wh, const float* __restrict__ b_h,
    const bfr* __restrict__ wz, const float* __restrict__ bzs,
    const bfr* __restrict__ wu, const float* __restrict__ b_u)
{
    __shared__ bfr s_hhu[12288];
    __shared__ bfr s_t[6144];
    tile_glob<false>(blockIdx.x * 64, ch, nullptr, c16_own, u_io,
                     wu, b_u, wr, brs, wh, b_h, wz, bzs, s_hhu, s_t);
}

// ========= fused (256,1) variant: register-persistent weights ========
__device__ __forceinline__ void load_wregs(
    const bfr* __restrict__ wr, const bfr* __restrict__ wh, const bfr* __restrict__ wz,
    const bfr* __restrict__ wu, int w, int q, int ln,
    bf16x8 (&Af)[3][6], bf16x8 (&Ah)[6], bf16x8 (&Aw)[4][8], bf16x8& awu)
{
#pragma unroll
    for (int nt = 0; nt < 3; ++nt)
#pragma unroll
        for (int kt = 0; kt < 6; ++kt)
            Af[nt][kt] = *(const bf16x8*)&wr[fidx(w * 3 + nt, kt, q, ln, 6)];
#pragma unroll
    for (int kt = 0; kt < 6; ++kt)
        Ah[kt] = *(const bf16x8*)&wh[fidx(w, kt, q, ln, 6)];
#pragma unroll
    for (int g = 0; g < 4; ++g)
#pragma unroll
        for (int kt = 0; kt < 8; ++kt)
            Aw[g][kt] = *(const bf16x8*)&wz[fidx(g * 4 + w, kt, q, ln, 8)];
    awu = *(const bf16x8*)&wu[fidx(w, 0, q, ln, 1)];
}

// CH_LDS = children come from s_t staging rows of the previous level tile
// (block-local binary-tree locality) instead of a global round-trip.
// STORE_U = emit the coalesced global store (only needed when a later
// KERNEL reads this level: u2). Entry __syncthreads covers the s_t handoff.
template <bool CH_LDS, bool STORE_U>
__device__ __forceinline__ void tile_regs(
    int row0, int rows,
    const bfr* __restrict__ ch, const bfr* __restrict__ c16_own,
    bfr* __restrict__ u_io,
    const bf16x8 awu, const float* __restrict__ b_u,
    const bf16x8 (&Af)[3][6], const bf16x8 (&Ah)[6], const bf16x8 (&Aw)[4][8],
    const float* __restrict__ brs, const float* __restrict__ b_h,
    const float* __restrict__ bzs,
    float* __restrict__ outp, bfr* s_hhu, bfr* s_t, bfr* s_hH)
{
    const int tid = threadIdx.x;
    const int lane = tid & 63, w = tid >> 6;
    const int ln = lane & 15, q = lane >> 4;
    const int Mtn = (rows + 15) >> 4;
    const int colbase = w * 16 + q * 4;

    __syncthreads();   // chain: prior tile's s_t writes/reads + global RAW

    // ---- phase A: children -> s_hhu frags + own u ----
#pragma unroll
    for (int it = 0; it < 4; ++it) {
        int idx = it * 256 + tid;
        int lns = idx & 15, qs = (idx >> 4) & 3, kts = (idx >> 6) & 3, Mts = idx >> 8;
        int row = Mts * 16 + lns;
        if (row < rows) {
            int k = kts * 32 + qs * 8;
            if (CH_LDS) {
                int crow = 2 * row + (k >= 64 ? 1 : 0);
                *(uint4*)&s_hhu[fidx(Mts, kts, qs, lns, 6)] =
                    *(const uint4*)&s_t[crow * OSTR + (k & 63)];
            } else {
                const bfr* src = (k < 64)
                    ? ch + (size_t)(2 * (row0 + row)) * 64 + k
                    : ch + (size_t)(2 * (row0 + row) + 1) * 64 + (k - 64);
                *(uint4*)&s_hhu[fidx(Mts, kts, qs, lns, 6)] = *(const uint4*)src;
            }
        }
    }
    {
        f32x4 bu4 = *(const f32x4*)&b_u[colbase];
#pragma unroll
        for (int Mt = 0; Mt < 4; ++Mt) {
            if (Mt < Mtn) {
                int row = Mt * 16 + ln;
                bf16x8 Bc = load_c_frag16(c16_own, (size_t)row0 + row, q == 0 && row < rows);
                f32x4 acc = {0.f, 0.f, 0.f, 0.f};
                acc = __builtin_amdgcn_mfma_f32_16x16x32_bf16(awu, Bc, acc, 0, 0, 0);
                int kk = 128 + colbase;
                int addr = fidx(Mt, kk >> 5, (kk >> 3) & 3, ln, 6) + (kk & 7);
                ushort uv[4];
#pragma unroll
                for (int r = 0; r < 4; ++r) uv[r] = f2bfr(fmaxf(acc[r] + bu4[r], 0.f));
                *(uint2*)&s_hhu[addr] = *(const uint2*)uv;
            }
        }
    }
    __syncthreads();

    // ---- mm1 ----
#pragma unroll
    for (int Mt = 0; Mt < 4; ++Mt) {
        if (Mt < Mtn) {
            bf16x8 Bf[6];
#pragma unroll
            for (int kt = 0; kt < 6; ++kt)
                Bf[kt] = *(const bf16x8*)&s_hhu[fidx(Mt, kt, q, ln, 6)];
#pragma unroll
            for (int nt = 0; nt < 3; ++nt) {
                int cb1 = (w * 3 + nt) * 16 + q * 4;
                f32x4 acc = {0.f, 0.f, 0.f, 0.f};
#pragma unroll
                for (int kt = 0; kt < 6; ++kt)
                    acc = __builtin_amdgcn_mfma_f32_16x16x32_bf16(Af[nt][kt], Bf[kt], acc, 0, 0, 0);
                f32x4 br4 = *(const f32x4*)&brs[cb1];
                int addr = fidx(Mt, cb1 >> 5, (cb1 >> 3) & 3, ln, 6) + (cb1 & 7);
                ushort hh[4], tt[4];
                *(uint2*)hh = *(const uint2*)&s_hhu[addr];
#pragma unroll
                for (int r = 0; r < 4; ++r) {
                    float e = fexp2(-(acc[r] + br4[r]));
                    tt[r] = f2bfr(frcp(1.f + e) * bfr2f(hh[r]));
                }
                *(uint2*)&s_t[addr] = *(const uint2*)tt;
            }
        }
    }
    __syncthreads();

    // ---- mm2 -> s_hH direct (separate region) ----
    {
        f32x4 bh4 = *(const f32x4*)&b_h[colbase];
#pragma unroll
        for (int Mt = 0; Mt < 4; ++Mt) {
            if (Mt < Mtn) {
                f32x4 acc = {0.f, 0.f, 0.f, 0.f};
#pragma unroll
                for (int kt = 0; kt < 6; ++kt) {
                    bf16x8 Bf = *(const bf16x8*)&s_t[fidx(Mt, kt, q, ln, 6)];
                    acc = __builtin_amdgcn_mfma_f32_16x16x32_bf16(Ah[kt], Bf, acc, 0, 0, 0);
                }
                int addr = fidx(Mt, colbase >> 5, (colbase >> 3) & 3, ln, 2) + (colbase & 7);
                ushort hv[4];
#pragma unroll
                for (int r = 0; r < 4; ++r) hv[r] = f2bfr(fmaxf(acc[r] + bh4[r], 0.f));
                *(uint2*)&s_hH[addr] = *(const uint2*)hv;
            }
        }
    }
    __syncthreads();

    // ---- mm3 per-Mt + gate -> stage rows in s_t ----
    {
        f32x4 bz0 = *(const f32x4*)&bzs[colbase];
        f32x4 bz1 = *(const f32x4*)&bzs[64 + colbase];
        f32x4 bz2 = *(const f32x4*)&bzs[128 + colbase];
        f32x4 bz3 = *(const f32x4*)&bzs[192 + colbase];
#pragma unroll
        for (int Mt = 0; Mt < 4; ++Mt) {
            if (Mt < Mtn) {
                bf16x8 Az[8];
                Az[0] = *(const bf16x8*)&s_hH[fidx(Mt, 0, q, ln, 2)];
                Az[1] = *(const bf16x8*)&s_hH[fidx(Mt, 1, q, ln, 2)];
#pragma unroll
                for (int kt = 0; kt < 6; ++kt)
                    Az[2 + kt] = *(const bf16x8*)&s_hhu[fidx(Mt, kt, q, ln, 6)];
                f32x4 azg[4];
#pragma unroll
                for (int g = 0; g < 4; ++g) {
                    f32x4 acc = {0.f, 0.f, 0.f, 0.f};
#pragma unroll
                    for (int kt = 0; kt < 8; ++kt)
                        acc = __builtin_amdgcn_mfma_f32_16x16x32_bf16(Aw[g][kt], Az[kt], acc, 0, 0, 0);
                    azg[g] = acc;
                }
                int row = Mt * 16 + ln;
                if (row < rows) {
                    int aH = fidx(Mt, colbase >> 5, (colbase >> 3) & 3, ln, 2) + (colbase & 7);
                    int a0 = fidx(Mt, colbase >> 5, (colbase >> 3) & 3, ln, 6) + (colbase & 7);
                    int c1 = 64 + colbase, c2 = 128 + colbase;
                    int a1 = fidx(Mt, c1 >> 5, (c1 >> 3) & 3, ln, 6) + (c1 & 7);
                    int a2 = fidx(Mt, c2 >> 5, (c2 >> 3) & 3, ln, 6) + (c2 & 7);
                    ushort hHv[4], u0[4], u1[4], u2[4], ov[4];
                    *(uint2*)hHv = *(const uint2*)&s_hH[aH];
                    *(uint2*)u0 = *(const uint2*)&s_hhu[a0];
                    *(uint2*)u1 = *(const uint2*)&s_hhu[a1];
                    *(uint2*)u2 = *(const uint2*)&s_hhu[a2];
                    float of[4];
#pragma unroll
                    for (int r = 0; r < 4; ++r) {
                        float e0 = fexp2(azg[0][r] + bz0[r]);
                        float e1 = fexp2(azg[1][r] + bz1[r]);
                        float e2 = fexp2(azg[2][r] + bz2[r]);
                        float e3 = fexp2(azg[3][r] + bz3[r]);
                        float inv = frcp(e0 + e1 + e2 + e3);
                        float v = (e0 * bfr2f(hHv[r]) + e1 * bfr2f(u0[r]) +
                                   e2 * bfr2f(u1[r]) + e3 * bfr2f(u2[r])) * inv;
                        ov[r] = f2bfr(v); of[r] = v;
                    }
                    *(uint2*)&s_t[row * OSTR + colbase] = *(const uint2*)ov;
                    if (outp)
                        *(float4*)&outp[(size_t)(row0 + row) * 64 + colbase] = *(const float4*)of;
                }
            }
        }
    }
    if (STORE_U) {
        __syncthreads();
        const int tid2 = threadIdx.x;
#pragma unroll
        for (int it = 0; it < 2; ++it) {
            int idx = it * 256 + tid2;
            int row = idx >> 3, ck = idx & 7;
            if (row < rows)
                *(uint4*)&u_io[(size_t)(row0 + row) * 64 + ck * 8] =
                    *(const uint4*)&s_t[row * OSTR + ck * 8];
        }
    }
}

// j=8..2, B=256 blocks; register-persistent weights; LDS-chained levels.
__global__ __launch_bounds__(256, 1) void fused_mid_regs(
    const bfr* __restrict__ c16, bfr* __restrict__ u_all,
    const bfr* __restrict__ wr, const float* __restrict__ brs,
    const bfr* __restrict__ wh, const float* __restrict__ b_h,
    const bfr* __restrict__ wz, const float* __restrict__ bzs,
    const bfr* __restrict__ wu, const float* __restrict__ b_u)
{
    __shared__ bfr s_hhu[12288];
    __shared__ bfr s_t[12288];
    __shared__ bfr s_hH[4096];
    const int tid = threadIdx.x;
    const int lane = tid & 63, w = tid >> 6, ln = lane & 15, q = lane >> 4;
    bf16x8 Af[3][6], Ah[6], Aw[4][8], awu;
    load_wregs(wr, wh, wz, wu, w, q, ln, Af, Ah, Aw, awu);
    // j=8: children from global u9 (cross-kernel); no global store of u8
    {
        const bfr* c16_8 = c16 + (size_t)((64 << 8) - 64) * 8;
        tile_regs<false, false>(blockIdx.x * 64, 64,
                                u_all + lvloff(9), c16_8, u_all + lvloff(8),
                                awu, b_u, Af, Ah, Aw, brs, b_h, bzs,
                                nullptr, s_hhu, s_t, s_hH);
    }
    // j=7..3: LDS-chained, no global stores
    for (int j = 7; j >= 3; --j) {
        int rows = 1 << (j - 2);   // 32..2
        const bfr* c16_own = c16 + (size_t)((64 << j) - 64) * 8;
        tile_regs<true, false>(blockIdx.x * rows, rows,
                               nullptr, c16_own, u_all + lvloff(j),
                               awu, b_u, Af, Ah, Aw, brs, b_h, bzs,
                               nullptr, s_hhu, s_t, s_hH);
    }
    // j=2: LDS-chained input, but u2 is read by fused_tail -> store it
    {
        const bfr* c16_2 = c16 + (size_t)((64 << 2) - 64) * 8;
        tile_regs<true, true>(blockIdx.x, 1,
                              nullptr, c16_2, u_all + lvloff(2),
                              awu, b_u, Af, Ah, Aw, brs, b_h, bzs,
                              nullptr, s_hhu, s_t, s_hH);
    }
}

// j=1..0, B=64 blocks.
__global__ __launch_bounds__(256, 1) void fused_tail_regs(
    const bfr* __restrict__ c16, bfr* __restrict__ u_all,
    const bfr* __restrict__ wr, const float* __restrict__ brs,
    const bfr* __restrict__ wh, const float* __restrict__ b_h,
    const bfr* __restrict__ wz, const float* __restrict__ bzs,
    const bfr* __restrict__ wu, const float* __restrict__ b_u,
    float* __restrict__ outp)
{
    __shared__ bfr s_hhu[12288];
    __shared__ bfr s_t[12288];
    __shared__ bfr s_hH[4096];
    const int tid = threadIdx.x;
    const int lane = tid & 63, w = tid >> 6, ln = lane & 15, q = lane >> 4;
    bf16x8 Af[3][6], Ah[6], Aw[4][8], awu;
    load_wregs(wr, wh, wz, wu, w, q, ln, Af, Ah, Aw, awu);
    // j=1: children from global u2 (cross-kernel); no store of u1
    {
        const bfr* c16_1 = c16 + (size_t)((64 << 1) - 64) * 8;
        tile_regs<false, false>(blockIdx.x * 2, 2,
                                u_all + lvloff(2), c16_1, u_all + lvloff(1),
                                awu, b_u, Af, Ah, Aw, brs, b_h, bzs,
                                nullptr, s_hhu, s_t, s_hH);
    }
    // j=0: LDS-chained; final result -> outp (f32); no u store
    {
        tile_regs<true, false>(blockIdx.x, 1,
                               nullptr, c16, u_all + lvloff(0),
                               awu, b_u, Af, Ah, Aw, brs, b_h, bzs,
                               outp, s_hhu, s_t, s_hH);
    }
}

extern "C" void kernel_launch(void* const* d_in, const int* in_sizes, int n_in,
                              void* d_out, int out_size, void* d_ws, size_t ws_size,
                              hipStream_t stream) {
    const float* contents = (const float*)d_in[0];
    const float* W_u = (const float*)d_in[1];
    const float* b_u = (const float*)d_in[2];
    const float* W_r = (const float*)d_in[3];
    const float* b_r = (const float*)d_in[4];
    const float* W_h = (const float*)d_in[5];
    const float* b_h = (const float*)d_in[6];
    const float* W_z = (const float*)d_in[7];
    const float* b_z = (const float*)d_in[8];
    float* out = (float*)d_out;

    // ws: u_all up-regions | packed weights | scaled biases
    // c16 (preconverted contents, 8.4MB) lives in the never-materialized
    // u12 region of u_all.
    bfr* u_all = (bfr*)d_ws;
    bfr* wr = u_all + (size_t)524224 * 64;
    bfr* wh = wr + 36864;
    bfr* wz = wh + 12288;
    float* brs = (float*)(wz + 65536);
    float* bzs = brs + 192;
    bfr* wu = (bfr*)(bzs + 256);
    bfr* c16 = u_all + lvloff(12);

    convert_inputs<<<2048, 256, 0, stream>>>(contents, c16,
                                             W_r, W_h, W_z, W_u, b_r, b_z,
                                             wr, wh, wz, wu, brs, bzs);

    const bfr* c16_12 = c16 + (size_t)((64 << 12) - 64) * 8;
    const bfr* c16_11 = c16 + (size_t)((64 << 11) - 64) * 8;
    const bfr* c16_10 = c16 + (size_t)((64 << 10) - 64) * 8;
    const bfr* c16_9  = c16 + (size_t)((64 << 9)  - 64) * 8;

    level11_kernel<<<2048, 256, 0, stream>>>(c16_12, c16_11, u_all + lvloff(11),
                                             wr, brs, wh, b_h, wz, bzs, wu, b_u);
    level_kernel<<<1024, 256, 0, stream>>>(u_all + lvloff(11), c16_10, u_all + lvloff(10),
                                           wr, brs, wh, b_h, wz, bzs, wu, b_u);
    level_kernel<<<512, 256, 0, stream>>>(u_all + lvloff(10), c16_9, u_all + lvloff(9),
                                          wr, brs, wh, b_h, wz, bzs, wu, b_u);
    fused_mid_regs<<<256, 256, 0, stream>>>(c16, u_all,
                                            wr, brs, wh, b_h, wz, bzs, wu, b_u);
    fused_tail_regs<<<64, 256, 0, stream>>>(c16, u_all,
                                            wr, brs, wh, b_h, wz, bzs, wu, b_u, out);
}

// Round 9
// 193.273 us; speedup vs baseline: 1.0291x; 1.0291x over previous
//
#include <hip/hip_runtime.h>
#include <hip/hip_bf16.h>

// GRNNTransformGated, round 29: 36KB split-t body + (256,4) + mm3 rewritten
// as INCREMENTAL softmax (num/den accumulators, 32 regs) so the tile truly
// fits the 64-VGPR occupancy class -> 4 blocks/CU without R27's spill.
// Post-mortem ledger:
//  R4: agent-scope spin grid barriers ~137us each -> never.
//  R12+R27: VGPR budget below live-acc arithmetic == spill. Spill tell =
//      WRITE_SIZE >> data written.
//  R13/R14: fusing big levels at 1-block/CU occupancy loses.
//  R15: +8KB LDS cost a block/CU on big levels. s_hH aliases s_t in glob.
//  R16+R25: per-lane loads feeding MFMA put global latency on the MFMA dep
//      chain -> regression. Cooperative staging + barrier wins. Direct 8B
//      stores at 128B stride lose to LDS-round-trip coalesced 16B stores.
//  R21 FAILED: weight prefetch under (256,2) -> compiler sank loads.
//  R22 FAILED: resident weights under (256,2): VGPR pinned, 700MB scratch.
//  R23 FAILED: merged-level kernel spilled (cross-tile scheduling).
//  R26 WIN (194.9, best): R24 bodies + one convert + CH_LDS fused chain.
//  R27/R28 matrix (same 36KB split-t body):
//      (256,4): VGPR 64, occ 33%, level11 49.5 (tiny az spill ~21B/thread)
//      (256,2): VGPR 92, occ 18.6%, level11 57.8 (no spill, NO 4th block)
//      RULE: gfx950 occupancy-relevant VGPR classes are <=64/<=128/<=256;
//      a 92-VGPR kernel occupies like 128. The 4-block config REQUIRES the
//      64-class. Split-t without the 4th block is a pure ~3us loss.
//  R29 (this round): make 64-class clean. mm3: az[4][4] (64 live regs) ->
//      num[4]/den[4] (32 live) accumulated across g (softmax is g-assoc-
//      order-preserving -> bit-identical). Aw[8] transient per g. Keep
//      (256,4). GUARDS: WRITE must be ~16.4MB (spill gone; else revert to
//      R26); VGPR must read 64.
// Carried: in-place up regions in u_all; exp2-folded W_r/b_r/W_z/b_z;
// operand-swapped MFMA (D = W @ act^T); coalesced up-store via LDS
// round-trip; MFMA-u; j=11 computes level-12 children u from c16; c16 in
// u12's never-used region; fused (256,1) chain j=8..0 with resident
// weights + CH_LDS/STORE_U.

#define LOG2E 1.4426950408889634f
#define OSTR 76   // out-staging row stride (elements)

typedef __bf16 bf16x8 __attribute__((ext_vector_type(8)));
typedef unsigned short u16x8 __attribute__((ext_vector_type(8)));
typedef float f32x4 __attribute__((ext_vector_type(4)));
typedef unsigned short bfr;   // raw bf16 bits

__device__ __forceinline__ float bfr2f(bfr v) { return __uint_as_float(((unsigned)v) << 16); }
__device__ __forceinline__ bfr f2bfr(float f) {
    __hip_bfloat16 h = __float2bfloat16(f);
    return __builtin_bit_cast(bfr, h);
}
__device__ __forceinline__ float fexp2(float x) {
#if __has_builtin(__builtin_amdgcn_exp2f)
    return __builtin_amdgcn_exp2f(x);
#else
    return exp2f(x);
#endif
}
__device__ __forceinline__ float frcp(float x) {
#if __has_builtin(__builtin_amdgcn_rcpf)
    return __builtin_amdgcn_rcpf(x);
#else
    return 1.f / x;
#endif
}

// fragment-order address (elements): frag (Mt,kt), lane (ln,q), 8 elems
__device__ __forceinline__ int fidx(int Mt, int kt, int q, int ln, int KT) {
    return ((((Mt * KT + kt) * 4 + q) * 16 + ln) * 8);
}

// level-j up region start (elements) within u_all
__device__ __host__ __forceinline__ size_t lvloff(int j) {
    return (size_t)((64 << j) - 64) * 64;
}

__device__ __forceinline__ void pack_one(const float* __restrict__ W, bfr* __restrict__ dst,
                                         int d, int K, float scale) {
    int KT = K >> 5;
    int j = d & 7, lnc = (d >> 3) & 15, q = (d >> 7) & 3;
    int t1 = d >> 9;
    int kt = t1 % KT, ntile = t1 / KT;
    int ncol = ntile * 16 + lnc;
    int k = kt * 32 + q * 8 + j;
    dst[d] = f2bfr(W[(size_t)ncol * K + k] * scale);
}

// One prologue kernel: weights pack + contents->c16. Grid 2048x256.
__global__ void convert_inputs(
    const float* __restrict__ c, bfr* __restrict__ c16,
    const float* __restrict__ Wr, const float* __restrict__ Wh,
    const float* __restrict__ Wz, const float* __restrict__ Wu,
    const float* __restrict__ br, const float* __restrict__ bz,
    bfr* __restrict__ wr, bfr* __restrict__ wh, bfr* __restrict__ wz,
    bfr* __restrict__ wu, float* __restrict__ brs, float* __restrict__ bzs)
{
    int i = blockIdx.x * 256 + threadIdx.x;   // 524288 threads
    if (i < 524224) {   // contents row -> padded bf16 row (16B)
        const float* cp = c + (size_t)i * 7;
        ushort v[8];
#pragma unroll
        for (int k = 0; k < 7; ++k) v[k] = f2bfr(cp[k]);
        v[7] = 0;
        *(uint4*)&c16[(size_t)i * 8] = *(const uint4*)v;
    }
    if (i < 36864) pack_one(Wr, wr, i, 192, LOG2E);
    if (i < 12288) pack_one(Wh, wh, i, 192, 1.f);
    if (i < 65536) pack_one(Wz, wz, i, 256, LOG2E);
    if (i < 2048) {   // W_u (64x7) -> frag order K=32, zero-padded
        int j = i & 7, lnc = (i >> 3) & 15, q = (i >> 7) & 3, ntile = i >> 9;
        int k = q * 8 + j, ncol = ntile * 16 + lnc;
        wu[i] = (k < 7) ? f2bfr(Wu[ncol * 7 + k]) : (bfr)0;
    }
    if (i < 192) brs[i] = br[i] * LOG2E;
    if (i < 256) bzs[i] = bz[i] * LOG2E;
}

// Stage `rows` pre-converted contents rows as bf16 B-frags (K=32 padded).
__device__ __forceinline__ void stage_c16(const bfr* __restrict__ c16src, int rows,
                                          bfr* s_c) {
    const int tid = threadIdx.x;
    for (int t = tid; t < rows * 4; t += 256) {
        int row = t >> 2, qg = t & 3;
        uint4 v = {0u, 0u, 0u, 0u};
        if (qg == 0) v = *(const uint4*)&c16src[(size_t)row * 8];
        *(uint4*)&s_c[(((row >> 4) * 4 + qg) * 16 + (row & 15)) * 8] = v;
    }
}

// Build a contents B-fragment directly from c16 (single 16B load).
// Used ONLY in the (256,1) fused tiles (R16/R25: staged wins in glob).
__device__ __forceinline__ bf16x8 load_c_frag16(const bfr* __restrict__ c16,
                                                size_t grow, bool active) {
    uint4 v = {0u, 0u, 0u, 0u};
    if (active) v = *(const uint4*)&c16[grow * 8];
    return __builtin_bit_cast(bf16x8, v);
}

// Coalesced up-store epilogue via LDS round-trip (internal syncs).
__device__ __forceinline__ void store_up_coalesced(
    int row0, int rows, bfr* __restrict__ u_io,
    const ushort (&ovv)[4][4], int Mtn, bfr* s_t)
{
    const int tid = threadIdx.x;
    const int lane = tid & 63, w = tid >> 6;
    const int ln = lane & 15, q = lane >> 4;
    const int colbase = w * 16 + q * 4;
    __syncthreads();
#pragma unroll
    for (int Mt = 0; Mt < 4; ++Mt) {
        if (Mt < Mtn) {
            int row = Mt * 16 + ln;
            if (row < rows)
                *(uint2*)&s_t[row * OSTR + colbase] = *(const uint2*)ovv[Mt];
        }
    }
    __syncthreads();
#pragma unroll
    for (int it = 0; it < 2; ++it) {
        int idx = it * 256 + tid;
        int row = idx >> 3, ck = idx & 7;
        if (row < rows)
            *(uint4*)&u_io[(size_t)(row0 + row) * 64 + ck * 8] =
                *(const uint4*)&s_t[row * OSTR + ck * 8];
    }
}

// mm_u: u = relu(c @ W_u^T) via MFMA from staged c frags into s_hhu (kt4..5).
__device__ __forceinline__ void mmu_own(const bfr* s_c, bfr* s_hhu, bf16x8 awu,
                                        f32x4 bu4, int Mtn, int ln, int q,
                                        int colbase) {
#pragma unroll
    for (int Mt = 0; Mt < 4; ++Mt) {
        if (Mt < Mtn) {
            bf16x8 Bc = *(const bf16x8*)&s_c[((Mt * 4 + q) * 16 + ln) * 8];
            f32x4 acc = {0.f, 0.f, 0.f, 0.f};
            acc = __builtin_amdgcn_mfma_f32_16x16x32_bf16(awu, Bc, acc, 0, 0, 0);
            int kk = 128 + colbase;
            int addr = fidx(Mt, kk >> 5, (kk >> 3) & 3, ln, 6) + (kk & 7);
            ushort uv[4];
#pragma unroll
            for (int r = 0; r < 4; ++r) uv[r] = f2bfr(fmaxf(acc[r] + bu4[r], 0.f));
            *(uint2*)&s_hhu[addr] = *(const uint2*)uv;
        }
    }
}

// ===== glob tile (R29): split-t mm1/mm2 K-halves, 36KB LDS, incremental
// softmax mm3 (num/den, 32 live regs) -> fits 64-VGPR occupancy class =====
template <bool CHILD_U>
__device__ __forceinline__ void tile_glob(
    int row0,
    const bfr* __restrict__ ch, const bfr* __restrict__ c16_child,
    const bfr* __restrict__ c16_own, bfr* __restrict__ u_io,
    const bfr* __restrict__ wu, const float* __restrict__ b_u,
    const bfr* __restrict__ wr, const float* __restrict__ brs,
    const bfr* __restrict__ wh, const float* __restrict__ b_h,
    const bfr* __restrict__ wz, const float* __restrict__ bzs,
    bfr* s_hhu, bfr* s_t)
{
    bfr* s_hH = s_t;   // alias: h_H (4KB) written only after t halves dead
    const int tid = threadIdx.x;
    const int lane = tid & 63, w = tid >> 6;
    const int ln = lane & 15, q = lane >> 4;
    const int colbase = w * 16 + q * 4;

    // ---- stage children + own contents (cooperative) ----
    if (!CHILD_U) {
#pragma unroll
        for (int it = 0; it < 4; ++it) {
            int idx = it * 256 + tid;
            int lns = idx & 15, qs = (idx >> 4) & 3, kts = (idx >> 6) & 3, Mts = idx >> 8;
            int row = Mts * 16 + lns;
            int k = kts * 32 + qs * 8;
            const bfr* src = (k < 64)
                ? ch + (size_t)(2 * (row0 + row)) * 64 + k
                : ch + (size_t)(2 * (row0 + row) + 1) * 64 + (k - 64);
            *(uint4*)&s_hhu[fidx(Mts, kts, qs, lns, 6)] = *(const uint4*)src;
        }
    } else {
        stage_c16(c16_child + (size_t)(2 * row0) * 8, 128, s_t + 2048);
    }
    stage_c16(c16_own + (size_t)row0 * 8, 64, s_t);
    __syncthreads();   // B1

    // ---- mm_u ----
    {
        bf16x8 awu = *(const bf16x8*)&wu[fidx(w, 0, q, ln, 1)];
        f32x4 bu4 = *(const f32x4*)&b_u[colbase];
        if (CHILD_U) {
#pragma unroll
            for (int Mt = 0; Mt < 8; ++Mt) {
                bf16x8 Bc = *(const bf16x8*)&s_t[2048 + (((Mt * 4 + q) * 16 + ln) * 8)];
                f32x4 acc = {0.f, 0.f, 0.f, 0.f};
                acc = __builtin_amdgcn_mfma_f32_16x16x32_bf16(awu, Bc, acc, 0, 0, 0);
                int crow = Mt * 16 + ln;
                int row = crow >> 1;
                int kk = (crow & 1) * 64 + colbase;
                int addr = fidx(row >> 4, kk >> 5, (kk >> 3) & 3, row & 15, 6) + (kk & 7);
                ushort uv[4];
#pragma unroll
                for (int r = 0; r < 4; ++r) uv[r] = f2bfr(fmaxf(acc[r] + bu4[r], 0.f));
                *(uint2*)&s_hhu[addr] = *(const uint2*)uv;
            }
        }
        mmu_own(s_t, s_hhu, awu, bu4, 4, ln, q, colbase);
    }
    __syncthreads();   // B2 (stage reads done; t halves may overwrite s_t)

    // ---- mm1/mm2 in two kt-halves through the 12KB t buffer ----
    f32x4 hacc[4];
#pragma unroll
    for (int Mt = 0; Mt < 4; ++Mt) hacc[Mt] = (f32x4){0.f, 0.f, 0.f, 0.f};
#pragma unroll
    for (int h = 0; h < 2; ++h) {
        // mm1 half h: col-tiles T = i*4+w with T in [6h, 6h+6)
#pragma unroll
        for (int i = 0; i < 3; ++i) {
            int T = i * 4 + w;
            if (T >= 6 * h && T < 6 * (h + 1)) {   // wave-uniform branch
                bf16x8 Af[6];
#pragma unroll
                for (int kt = 0; kt < 6; ++kt)
                    Af[kt] = *(const bf16x8*)&wr[fidx(T, kt, q, ln, 6)];
                int cb1 = T * 16 + q * 4;
                f32x4 br4 = *(const f32x4*)&brs[cb1];
#pragma unroll
                for (int Mt = 0; Mt < 4; ++Mt) {
                    f32x4 acc = {0.f, 0.f, 0.f, 0.f};
#pragma unroll
                    for (int kt = 0; kt < 6; ++kt)
                        acc = __builtin_amdgcn_mfma_f32_16x16x32_bf16(
                            Af[kt], *(const bf16x8*)&s_hhu[fidx(Mt, kt, q, ln, 6)], acc, 0, 0, 0);
                    int addrh = fidx(Mt, cb1 >> 5, (cb1 >> 3) & 3, ln, 6) + (cb1 & 7);
                    int addrt = fidx(Mt, (T >> 1) - 3 * h, (cb1 >> 3) & 3, ln, 3) + (cb1 & 7);
                    ushort hh[4], tt[4];
                    *(uint2*)hh = *(const uint2*)&s_hhu[addrh];
#pragma unroll
                    for (int r = 0; r < 4; ++r) {
                        float e = fexp2(-(acc[r] + br4[r]));
                        tt[r] = f2bfr(frcp(1.f + e) * bfr2f(hh[r]));
                    }
                    *(uint2*)&s_t[addrt] = *(const uint2*)tt;
                }
            }
        }
        __syncthreads();   // t half ready
        // mm2 half h: accumulate kt = 3h..3h+2
        {
            bf16x8 Ah[3];
#pragma unroll
            for (int k3 = 0; k3 < 3; ++k3)
                Ah[k3] = *(const bf16x8*)&wh[fidx(w, 3 * h + k3, q, ln, 6)];
#pragma unroll
            for (int Mt = 0; Mt < 4; ++Mt) {
#pragma unroll
                for (int k3 = 0; k3 < 3; ++k3)
                    hacc[Mt] = __builtin_amdgcn_mfma_f32_16x16x32_bf16(
                        Ah[k3], *(const bf16x8*)&s_t[fidx(Mt, k3, q, ln, 3)], hacc[Mt], 0, 0, 0);
            }
        }
        __syncthreads();   // half reads done (next half / hH may overwrite)
    }

    // ---- hH write (aliased s_t; t dead) ----
    {
        f32x4 bh4 = *(const f32x4*)&b_h[colbase];
#pragma unroll
        for (int Mt = 0; Mt < 4; ++Mt) {
            int addr = fidx(Mt, colbase >> 5, (colbase >> 3) & 3, ln, 2) + (colbase & 7);
            ushort hv[4];
#pragma unroll
            for (int r = 0; r < 4; ++r) hv[r] = f2bfr(fmaxf(hacc[Mt][r] + bh4[r], 0.f));
            *(uint2*)&s_hH[addr] = *(const uint2*)hv;
        }
    }
    __syncthreads();

    // ---- mm3: incremental softmax (num/den across g; bit-identical
    // left-assoc order) + gate. Live: num[4]+den[4] = 32 regs. ----
    {
        f32x4 num[4], den[4];
#pragma unroll
        for (int Mt = 0; Mt < 4; ++Mt) {
            num[Mt] = (f32x4){0.f, 0.f, 0.f, 0.f};
            den[Mt] = (f32x4){0.f, 0.f, 0.f, 0.f};
        }
#pragma unroll
        for (int g = 0; g < 4; ++g) {
            bf16x8 Aw[8];
#pragma unroll
            for (int kt = 0; kt < 8; ++kt)
                Aw[kt] = *(const bf16x8*)&wz[fidx(g * 4 + w, kt, q, ln, 8)];
            f32x4 bzg = *(const f32x4*)&bzs[g * 64 + colbase];
#pragma unroll
            for (int Mt = 0; Mt < 4; ++Mt) {
                f32x4 acc = {0.f, 0.f, 0.f, 0.f};
                acc = __builtin_amdgcn_mfma_f32_16x16x32_bf16(
                    Aw[0], *(const bf16x8*)&s_hH[fidx(Mt, 0, q, ln, 2)], acc, 0, 0, 0);
                acc = __builtin_amdgcn_mfma_f32_16x16x32_bf16(
                    Aw[1], *(const bf16x8*)&s_hH[fidx(Mt, 1, q, ln, 2)], acc, 0, 0, 0);
#pragma unroll
                for (int kt = 0; kt < 6; ++kt)
                    acc = __builtin_amdgcn_mfma_f32_16x16x32_bf16(
                        Aw[2 + kt], *(const bf16x8*)&s_hhu[fidx(Mt, kt, q, ln, 6)], acc, 0, 0, 0);
                // gate value fragment for this g (g=0: h_H; 1: h_L; 2: h_R; 3: u)
                ushort vv[4];
                if (g == 0) {
                    int aH = fidx(Mt, colbase >> 5, (colbase >> 3) & 3, ln, 2) + (colbase & 7);
                    *(uint2*)vv = *(const uint2*)&s_hH[aH];
                } else {
                    int cc = (g - 1) * 64 + colbase;
                    int av = fidx(Mt, cc >> 5, (cc >> 3) & 3, ln, 6) + (cc & 7);
                    *(uint2*)vv = *(const uint2*)&s_hhu[av];
                }
#pragma unroll
                for (int r = 0; r < 4; ++r) {
                    float e = fexp2(acc[r] + bzg[r]);
                    num[Mt][r] += e * bfr2f(vv[r]);
                    den[Mt][r] += e;
                }
            }
        }
        ushort ovv[4][4];
#pragma unroll
        for (int Mt = 0; Mt < 4; ++Mt) {
#pragma unroll
            for (int r = 0; r < 4; ++r)
                ovv[Mt][r] = f2bfr(num[Mt][r] * frcp(den[Mt][r]));
        }
        store_up_coalesced(row0, 64, u_io, ovv, 4, s_t);
    }
}

__global__ __launch_bounds__(256, 4) void level11_kernel(
    const bfr* __restrict__ c16_12, const bfr* __restrict__ c16_11,
    bfr* __restrict__ u_io,
    const bfr* __restrict__ wr, const float* __restrict__ brs,
    const bfr* __restrict__ wh, const float* __restrict__ b_h,
    const bfr* __restrict__ wz, const float* __restrict__ bzs,
    const bfr* __restrict__ wu, const float* __restrict__ b_u)
{
    __shared__ bfr s_hhu[12288];
    __shared__ bfr s_t[6144];
    tile_glob<true>(blockIdx.x * 64, nullptr, c16_12, c16_11, u_io,
                    wu, b_u, wr, brs, wh, b_h, wz, bzs, s_hhu, s_t);
}

__global__ __launch_bounds__(256, 4) void level_kernel(
    const bfr* __restrict__ ch, const bfr* __restrict__ c16_own,
    bfr* __restrict__ u_io,
    const bfr* __restrict__ wr, const float* __restrict__ brs,
    const bfr* __restrict__ wh, const float* __restrict__ b_h,
    const bfr* __restrict__ wz, const float* __restrict__ bzs,
    const bfr* __restrict__ wu, const float* __restrict__ b_u)
{
    __shared__ bfr s_hhu[12288];
    __shared__ bfr s_t[6144];
    tile_glob<false>(blockIdx.x * 64, ch, nullptr, c16_own, u_io,
                     wu, b_u, wr, brs, wh, b_h, wz, bzs, s_hhu, s_t);
}

// ========= fused (256,1) variant: register-persistent weights ========
__device__ __forceinline__ void load_wregs(
    const bfr* __restrict__ wr, const bfr* __restrict__ wh, const bfr* __restrict__ wz,
    const bfr* __restrict__ wu, int w, int q, int ln,
    bf16x8 (&Af)[3][6], bf16x8 (&Ah)[6], bf16x8 (&Aw)[4][8], bf16x8& awu)
{
#pragma unroll
    for (int nt = 0; nt < 3; ++nt)
#pragma unroll
        for (int kt = 0; kt < 6; ++kt)
            Af[nt][kt] = *(const bf16x8*)&wr[fidx(w * 3 + nt, kt, q, ln, 6)];
#pragma unroll
    for (int kt = 0; kt < 6; ++kt)
        Ah[kt] = *(const bf16x8*)&wh[fidx(w, kt, q, ln, 6)];
#pragma unroll
    for (int g = 0; g < 4; ++g)
#pragma unroll
        for (int kt = 0; kt < 8; ++kt)
            Aw[g][kt] = *(const bf16x8*)&wz[fidx(g * 4 + w, kt, q, ln, 8)];
    awu = *(const bf16x8*)&wu[fidx(w, 0, q, ln, 1)];
}

// CH_LDS = children come from s_t staging rows of the previous level tile
// (block-local binary-tree locality) instead of a global round-trip.
// STORE_U = emit the coalesced global store (only needed when a later
// KERNEL reads this level: u2). Entry __syncthreads covers the s_t handoff.
template <bool CH_LDS, bool STORE_U>
__device__ __forceinline__ void tile_regs(
    int row0, int rows,
    const bfr* __restrict__ ch, const bfr* __restrict__ c16_own,
    bfr* __restrict__ u_io,
    const bf16x8 awu, const float* __restrict__ b_u,
    const bf16x8 (&Af)[3][6], const bf16x8 (&Ah)[6], const bf16x8 (&Aw)[4][8],
    const float* __restrict__ brs, const float* __restrict__ b_h,
    const float* __restrict__ bzs,
    float* __restrict__ outp, bfr* s_hhu, bfr* s_t, bfr* s_hH)
{
    const int tid = threadIdx.x;
    const int lane = tid & 63, w = tid >> 6;
    const int ln = lane & 15, q = lane >> 4;
    const int Mtn = (rows + 15) >> 4;
    const int colbase = w * 16 + q * 4;

    __syncthreads();   // chain: prior tile's s_t writes/reads + global RAW

    // ---- phase A: children -> s_hhu frags + own u ----
#pragma unroll
    for (int it = 0; it < 4; ++it) {
        int idx = it * 256 + tid;
        int lns = idx & 15, qs = (idx >> 4) & 3, kts = (idx >> 6) & 3, Mts = idx >> 8;
        int row = Mts * 16 + lns;
        if (row < rows) {
            int k = kts * 32 + qs * 8;
            if (CH_LDS) {
                int crow = 2 * row + (k >= 64 ? 1 : 0);
                *(uint4*)&s_hhu[fidx(Mts, kts, qs, lns, 6)] =
                    *(const uint4*)&s_t[crow * OSTR + (k & 63)];
            } else {
                const bfr* src = (k < 64)
                    ? ch + (size_t)(2 * (row0 + row)) * 64 + k
                    : ch + (size_t)(2 * (row0 + row) + 1) * 64 + (k - 64);
                *(uint4*)&s_hhu[fidx(Mts, kts, qs, lns, 6)] = *(const uint4*)src;
            }
        }
    }
    {
        f32x4 bu4 = *(const f32x4*)&b_u[colbase];
#pragma unroll
        for (int Mt = 0; Mt < 4; ++Mt) {
            if (Mt < Mtn) {
                int row = Mt * 16 + ln;
                bf16x8 Bc = load_c_frag16(c16_own, (size_t)row0 + row, q == 0 && row < rows);
                f32x4 acc = {0.f, 0.f, 0.f, 0.f};
                acc = __builtin_amdgcn_mfma_f32_16x16x32_bf16(awu, Bc, acc, 0, 0, 0);
                int kk = 128 + colbase;
                int addr = fidx(Mt, kk >> 5, (kk >> 3) & 3, ln, 6) + (kk & 7);
                ushort uv[4];
#pragma unroll
                for (int r = 0; r < 4; ++r) uv[r] = f2bfr(fmaxf(acc[r] + bu4[r], 0.f));
                *(uint2*)&s_hhu[addr] = *(const uint2*)uv;
            }
        }
    }
    __syncthreads();

    // ---- mm1 ----
#pragma unroll
    for (int Mt = 0; Mt < 4; ++Mt) {
        if (Mt < Mtn) {
            bf16x8 Bf[6];
#pragma unroll
            for (int kt = 0; kt < 6; ++kt)
                Bf[kt] = *(const bf16x8*)&s_hhu[fidx(Mt, kt, q, ln, 6)];
#pragma unroll
            for (int nt = 0; nt < 3; ++nt) {
                int cb1 = (w * 3 + nt) * 16 + q * 4;
                f32x4 acc = {0.f, 0.f, 0.f, 0.f};
#pragma unroll
                for (int kt = 0; kt < 6; ++kt)
                    acc = __builtin_amdgcn_mfma_f32_16x16x32_bf16(Af[nt][kt], Bf[kt], acc, 0, 0, 0);
                f32x4 br4 = *(const f32x4*)&brs[cb1];
                int addr = fidx(Mt, cb1 >> 5, (cb1 >> 3) & 3, ln, 6) + (cb1 & 7);
                ushort hh[4], tt[4];
                *(uint2*)hh = *(const uint2*)&s_hhu[addr];
#pragma unroll
                for (int r = 0; r < 4; ++r) {
                    float e = fexp2(-(acc[r] + br4[r]));
                    tt[r] = f2bfr(frcp(1.f + e) * bfr2f(hh[r]));
                }
                *(uint2*)&s_t[addr] = *(const uint2*)tt;
            }
        }
    }
    __syncthreads();

    // ---- mm2 -> s_hH direct (separate region) ----
    {
        f32x4 bh4 = *(const f32x4*)&b_h[colbase];
#pragma unroll
        for (int Mt = 0; Mt < 4; ++Mt) {
            if (Mt < Mtn) {
                f32x4 acc = {0.f, 0.f, 0.f, 0.f};
#pragma unroll
                for (int kt = 0; kt < 6; ++kt) {
                    bf16x8 Bf = *(const bf16x8*)&s_t[fidx(Mt, kt, q, ln, 6)];
                    acc = __builtin_amdgcn_mfma_f32_16x16x32_bf16(Ah[kt], Bf, acc, 0, 0, 0);
                }
                int addr = fidx(Mt, colbase >> 5, (colbase >> 3) & 3, ln, 2) + (colbase & 7);
                ushort hv[4];
#pragma unroll
                for (int r = 0; r < 4; ++r) hv[r] = f2bfr(fmaxf(acc[r] + bh4[r], 0.f));
                *(uint2*)&s_hH[addr] = *(const uint2*)hv;
            }
        }
    }
    __syncthreads();

    // ---- mm3 per-Mt + gate -> stage rows in s_t ----
    {
        f32x4 bz0 = *(const f32x4*)&bzs[colbase];
        f32x4 bz1 = *(const f32x4*)&bzs[64 + colbase];
        f32x4 bz2 = *(const f32x4*)&bzs[128 + colbase];
        f32x4 bz3 = *(const f32x4*)&bzs[192 + colbase];
#pragma unroll
        for (int Mt = 0; Mt < 4; ++Mt) {
            if (Mt < Mtn) {
                bf16x8 Az[8];
                Az[0] = *(const bf16x8*)&s_hH[fidx(Mt, 0, q, ln, 2)];
                Az[1] = *(const bf16x8*)&s_hH[fidx(Mt, 1, q, ln, 2)];
#pragma unroll
                for (int kt = 0; kt < 6; ++kt)
                    Az[2 + kt] = *(const bf16x8*)&s_hhu[fidx(Mt, kt, q, ln, 6)];
                f32x4 azg[4];
#pragma unroll
                for (int g = 0; g < 4; ++g) {
                    f32x4 acc = {0.f, 0.f, 0.f, 0.f};
#pragma unroll
                    for (int kt = 0; kt < 8; ++kt)
                        acc = __builtin_amdgcn_mfma_f32_16x16x32_bf16(Aw[g][kt], Az[kt], acc, 0, 0, 0);
                    azg[g] = acc;
                }
                int row = Mt * 16 + ln;
                if (row < rows) {
                    int aH = fidx(Mt, colbase >> 5, (colbase >> 3) & 3, ln, 2) + (colbase & 7);
                    int a0 = fidx(Mt, colbase >> 5, (colbase >> 3) & 3, ln, 6) + (colbase & 7);
                    int c1 = 64 + colbase, c2 = 128 + colbase;
                    int a1 = fidx(Mt, c1 >> 5, (c1 >> 3) & 3, ln, 6) + (c1 & 7);
                    int a2 = fidx(Mt, c2 >> 5, (c2 >> 3) & 3, ln, 6) + (c2 & 7);
                    ushort hHv[4], u0[4], u1[4], u2[4], ov[4];
                    *(uint2*)hHv = *(const uint2*)&s_hH[aH];
                    *(uint2*)u0 = *(const uint2*)&s_hhu[a0];
                    *(uint2*)u1 = *(const uint2*)&s_hhu[a1];
                    *(uint2*)u2 = *(const uint2*)&s_hhu[a2];
                    float of[4];
#pragma unroll
                    for (int r = 0; r < 4; ++r) {
                        float e0 = fexp2(azg[0][r] + bz0[r]);
                        float e1 = fexp2(azg[1][r] + bz1[r]);
                        float e2 = fexp2(azg[2][r] + bz2[r]);
                        float e3 = fexp2(azg[3][r] + bz3[r]);
                        float inv = frcp(e0 + e1 + e2 + e3);
                        float v = (e0 * bfr2f(hHv[r]) + e1 * bfr2f(u0[r]) +
                                   e2 * bfr2f(u1[r]) + e3 * bfr2f(u2[r])) * inv;
                        ov[r] = f2bfr(v); of[r] = v;
                    }
                    *(uint2*)&s_t[row * OSTR + colbase] = *(const uint2*)ov;
                    if (outp)
                        *(float4*)&outp[(size_t)(row0 + row) * 64 + colbase] = *(const float4*)of;
                }
            }
        }
    }
    if (STORE_U) {
        __syncthreads();
        const int tid2 = threadIdx.x;
#pragma unroll
        for (int it = 0; it < 2; ++it) {
            int idx = it * 256 + tid2;
            int row = idx >> 3, ck = idx & 7;
            if (row < rows)
                *(uint4*)&u_io[(size_t)(row0 + row) * 64 + ck * 8] =
                    *(const uint4*)&s_t[row * OSTR + ck * 8];
        }
    }
}

// j=8..2, B=256 blocks; register-persistent weights; LDS-chained levels.
__global__ __launch_bounds__(256, 1) void fused_mid_regs(
    const bfr* __restrict__ c16, bfr* __restrict__ u_all,
    const bfr* __restrict__ wr, const float* __restrict__ brs,
    const bfr* __restrict__ wh, const float* __restrict__ b_h,
    const bfr* __restrict__ wz, const float* __restrict__ bzs,
    const bfr* __restrict__ wu, const float* __restrict__ b_u)
{
    __shared__ bfr s_hhu[12288];
    __shared__ bfr s_t[12288];
    __shared__ bfr s_hH[4096];
    const int tid = threadIdx.x;
    const int lane = tid & 63, w = tid >> 6, ln = lane & 15, q = lane >> 4;
    bf16x8 Af[3][6], Ah[6], Aw[4][8], awu;
    load_wregs(wr, wh, wz, wu, w, q, ln, Af, Ah, Aw, awu);
    // j=8: children from global u9 (cross-kernel); no global store of u8
    {
        const bfr* c16_8 = c16 + (size_t)((64 << 8) - 64) * 8;
        tile_regs<false, false>(blockIdx.x * 64, 64,
                                u_all + lvloff(9), c16_8, u_all + lvloff(8),
                                awu, b_u, Af, Ah, Aw, brs, b_h, bzs,
                                nullptr, s_hhu, s_t, s_hH);
    }
    // j=7..3: LDS-chained, no global stores
    for (int j = 7; j >= 3; --j) {
        int rows = 1 << (j - 2);   // 32..2
        const bfr* c16_own = c16 + (size_t)((64 << j) - 64) * 8;
        tile_regs<true, false>(blockIdx.x * rows, rows,
                               nullptr, c16_own, u_all + lvloff(j),
                               awu, b_u, Af, Ah, Aw, brs, b_h, bzs,
                               nullptr, s_hhu, s_t, s_hH);
    }
    // j=2: LDS-chained input, but u2 is read by fused_tail -> store it
    {
        const bfr* c16_2 = c16 + (size_t)((64 << 2) - 64) * 8;
        tile_regs<true, true>(blockIdx.x, 1,
                              nullptr, c16_2, u_all + lvloff(2),
                              awu, b_u, Af, Ah, Aw, brs, b_h, bzs,
                              nullptr, s_hhu, s_t, s_hH);
    }
}

// j=1..0, B=64 blocks.
__global__ __launch_bounds__(256, 1) void fused_tail_regs(
    const bfr* __restrict__ c16, bfr* __restrict__ u_all,
    const bfr* __restrict__ wr, const float* __restrict__ brs,
    const bfr* __restrict__ wh, const float* __restrict__ b_h,
    const bfr* __restrict__ wz, const float* __restrict__ bzs,
    const bfr* __restrict__ wu, const float* __restrict__ b_u,
    float* __restrict__ outp)
{
    __shared__ bfr s_hhu[12288];
    __shared__ bfr s_t[12288];
    __shared__ bfr s_hH[4096];
    const int tid = threadIdx.x;
    const int lane = tid & 63, w = tid >> 6, ln = lane & 15, q = lane >> 4;
    bf16x8 Af[3][6], Ah[6], Aw[4][8], awu;
    load_wregs(wr, wh, wz, wu, w, q, ln, Af, Ah, Aw, awu);
    // j=1: children from global u2 (cross-kernel); no store of u1
    {
        const bfr* c16_1 = c16 + (size_t)((64 << 1) - 64) * 8;
        tile_regs<false, false>(blockIdx.x * 2, 2,
                                u_all + lvloff(2), c16_1, u_all + lvloff(1),
                                awu, b_u, Af, Ah, Aw, brs, b_h, bzs,
                                nullptr, s_hhu, s_t, s_hH);
    }
    // j=0: LDS-chained; final result -> outp (f32); no u store
    {
        tile_regs<true, false>(blockIdx.x, 1,
                               nullptr, c16, u_all + lvloff(0),
                               awu, b_u, Af, Ah, Aw, brs, b_h, bzs,
                               outp, s_hhu, s_t, s_hH);
    }
}

extern "C" void kernel_launch(void* const* d_in, const int* in_sizes, int n_in,
                              void* d_out, int out_size, void* d_ws, size_t ws_size,
                              hipStream_t stream) {
    const float* contents = (const float*)d_in[0];
    const float* W_u = (const float*)d_in[1];
    const float* b_u = (const float*)d_in[2];
    const float* W_r = (const float*)d_in[3];
    const float* b_r = (const float*)d_in[4];
    const float* W_h = (const float*)d_in[5];
    const float* b_h = (const float*)d_in[6];
    const float* W_z = (const float*)d_in[7];
    const float* b_z = (const float*)d_in[8];
    float* out = (float*)d_out;

    // ws: u_all up-regions | packed weights | scaled biases
    // c16 (preconverted contents, 8.4MB) lives in the never-materialized
    // u12 region of u_all.
    bfr* u_all = (bfr*)d_ws;
    bfr* wr = u_all + (size_t)524224 * 64;
    bfr* wh = wr + 36864;
    bfr* wz = wh + 12288;
    float* brs = (float*)(wz + 65536);
    float* bzs = brs + 192;
    bfr* wu = (bfr*)(bzs + 256);
    bfr* c16 = u_all + lvloff(12);

    convert_inputs<<<2048, 256, 0, stream>>>(contents, c16,
                                             W_r, W_h, W_z, W_u, b_r, b_z,
                                             wr, wh, wz, wu, brs, bzs);

    const bfr* c16_12 = c16 + (size_t)((64 << 12) - 64) * 8;
    const bfr* c16_11 = c16 + (size_t)((64 << 11) - 64) * 8;
    const bfr* c16_10 = c16 + (size_t)((64 << 10) - 64) * 8;
    const bfr* c16_9  = c16 + (size_t)((64 << 9)  - 64) * 8;

    level11_kernel<<<2048, 256, 0, stream>>>(c16_12, c16_11, u_all + lvloff(11),
                                             wr, brs, wh, b_h, wz, bzs, wu, b_u);
    level_kernel<<<1024, 256, 0, stream>>>(u_all + lvloff(11), c16_10, u_all + lvloff(10),
                                           wr, brs, wh, b_h, wz, bzs, wu, b_u);
    level_kernel<<<512, 256, 0, stream>>>(u_all + lvloff(10), c16_9, u_all + lvloff(9),
                                          wr, brs, wh, b_h, wz, bzs, wu, b_u);
    fused_mid_regs<<<256, 256, 0, stream>>>(c16, u_all,
                                            wr, brs, wh, b_h, wz, bzs, wu, b_u);
    fused_tail_regs<<<64, 256, 0, stream>>>(c16, u_all,
                                            wr, brs, wh, b_h, wz, bzs, wu, b_u, out);
}